// Round 7
// baseline (984.909 us; speedup 1.0000x reference)
//
#include <hip/hip_runtime.h>
#include <stdint.h>

typedef __attribute__((ext_vector_type(8))) short bhalf8;   // 8 bf16 (4 VGPR)
typedef __attribute__((ext_vector_type(4))) float floatx4;  // 4 f32 acc

#define BM 256
#define BN 128
#define BK 64
#define AST 72   // fallback kernel's padded A stride
#define BST 72   // B stride (padded)
#define NT 512

constexpr int Mdim = 8192;   // B*S
constexpr int Ndim = 11008;
constexpr int Kdim = 4096;
constexpr int NTILES = Kdim / BK;                      // 64
constexpr size_t XB_BYTES = (size_t)Mdim * Kdim * 2;   // 67,108,864

// packed f32x2 -> bf16x2 (RNE), single VALU inst (validated round 4)
__device__ __forceinline__ unsigned int cvt_pk_bf16(float lo, float hi) {
  unsigned int r;
  asm("v_cvt_pk_bf16_f32 %0, %1, %2" : "=v"(r) : "v"(lo), "v"(hi));
  return r;
}

// ---------------- prep: x f32 -> bf16 (memory-bound, ~40us) ----------------
__global__ __launch_bounds__(256)
void cvt_x_kernel(const float* __restrict__ x, unsigned short* __restrict__ xb) {
  const int nchunk = Mdim * Kdim / 8;            // 4,194,304
  const int stride = 2048 * 256;
  for (int c = blockIdx.x * 256 + threadIdx.x; c < nchunk; c += stride) {
    const float4 f0 = *(const float4*)(x + (size_t)c * 8);
    const float4 f1 = *(const float4*)(x + (size_t)c * 8 + 4);
    uint4 pk;
    pk.x = cvt_pk_bf16(f0.x, f0.y);
    pk.y = cvt_pk_bf16(f0.z, f0.w);
    pk.z = cvt_pk_bf16(f1.x, f1.y);
    pk.w = cvt_pk_bf16(f1.z, f1.w);
    *(uint4*)(xb + (size_t)c * 8) = pk;
  }
}

// ---- main: double-buffered fused-dequant GEMM (T3-minimum schedule) ----
// Per iteration t: compute tile t from buf p=t&1 while staging tile t+1 into
// buf p^1 (A via global_load_lds DMA, B via reg-dequant placed BETWEEN the two
// MFMA clusters). ONE barrier per tile; DMA latency hides under MFMA.
__global__ __launch_bounds__(NT, 1)
void qgemm_db(const unsigned short* __restrict__ xb,      // bf16 (M,K) in ws
              const unsigned int*   __restrict__ qweight, // (K/8, N)
              const unsigned int*   __restrict__ qzeros,  // (G, N/8)
              const float*          __restrict__ scales,  // f32 (G,N)
              const float*          __restrict__ bias,    // f32 (N)
              float*                __restrict__ out)     // f32 (M,N)
{
  __shared__ unsigned short As[2][BM * BK];    // 2 x 32 KB, linear (DMA dest)
  __shared__ unsigned short Bs[2][BN * BST];   // 2 x 18 KB, padded

  const int tid  = threadIdx.x;
  const int lane = tid & 63;
  const int wid  = tid >> 6;
  const int wm   = wid >> 1;        // 0..3
  const int wn   = wid & 1;         // 0..1
  const int fr   = lane & 15;
  const int kh   = lane >> 4;       // 0..3

  const int nbn = Ndim / BN;                    // 86
  const int nwg = (Mdim / BM) * nbn;            // 2752 (%8==0)
  const int bid = blockIdx.x;
  const int swz = (bid & 7) * (nwg >> 3) + (bid >> 3);
  const int m0  = (swz / nbn) * BM;
  const int n0  = (swz % nbn) * BN;

  // A DMA source: chunk c=i*NT+tid -> row=c>>3, slot=c&7, logical q=slot^(row&7)
  const unsigned short* asrc[4];
#pragma unroll
  for (int i = 0; i < 4; ++i) {
    const int c   = i * NT + tid;
    const int row = c >> 3;
    const int q   = (c & 7) ^ (row & 7);
    asrc[i] = xb + (size_t)(m0 + row) * Kdim + q * 8;
  }

  // B staging: 2 int32/thread, same column nn
  const int bc = tid & 127;
  const int br = tid >> 7;          // 0..3; rows br and br+4
  const int nn = n0 + bc;

  floatx4 acc[4][4] = {};

  // ---------------- prologue: stage tile 0 into buf 0 ----------------
  {
#pragma unroll
    for (int i = 0; i < 4; ++i)
      __builtin_amdgcn_global_load_lds(
          (const __attribute__((address_space(1))) void*)(asrc[i]),
          (__attribute__((address_space(3))) void*)(&As[0][(i * NT + tid) * 8]),
          16, 0, 0);
    const float        s0  = scales[nn];
    const unsigned int qz0 = qzeros[nn >> 3];
    const float        z0  = -(float)((qz0 >> ((nn & 7) * 4)) & 15u) * s0;
    unsigned int qv[2];
    qv[0] = qweight[(size_t)br       * Ndim + nn];
    qv[1] = qweight[(size_t)(br + 4) * Ndim + nn];
#pragma unroll
    for (int i = 0; i < 2; ++i) {
      const unsigned int q = qv[i];
      uint4 pk; unsigned int w[4];
#pragma unroll
      for (int j = 0; j < 4; ++j) {
        const float f0 = fmaf((float)((q >> (8 * j))     & 15u), s0, z0);
        const float f1 = fmaf((float)((q >> (8 * j + 4)) & 15u), s0, z0);
        w[j] = cvt_pk_bf16(f0, f1);
      }
      pk.x = w[0]; pk.y = w[1]; pk.z = w[2]; pk.w = w[3];
      *(uint4*)(&Bs[0][bc * BST + (br + i * 4) * 8]) = pk;
    }
  }
  __syncthreads();

  // ---------------- main loop ----------------
  unsigned int qv0 = 0, qv1 = 0;
  float sN = 0.f, zN = 0.f;

  for (int t = 0; t < NTILES; ++t) {
    const int p = t & 1;
    const unsigned short* Ac = As[p];
    const unsigned short* Bc = Bs[p];
    const bool more = (t + 1 < NTILES);

    // ---- stage issue for tile t+1 (loads fly under the MFMA below) ----
    if (more) {
      const int k1 = (t + 1) * BK;
      const int g  = k1 >> 7;
      sN = scales[(size_t)g * Ndim + nn];
      const unsigned int qzv = qzeros[(size_t)g * (Ndim / 8) + (nn >> 3)];
      zN = -(float)((qzv >> ((nn & 7) * 4)) & 15u) * sN;
      qv0 = qweight[(size_t)(k1 / 8 + br)     * Ndim + nn];
      qv1 = qweight[(size_t)(k1 / 8 + br + 4) * Ndim + nn];
#pragma unroll
      for (int i = 0; i < 4; ++i)
        __builtin_amdgcn_global_load_lds(
            (const __attribute__((address_space(1))) void*)(asrc[i] + k1),
            (__attribute__((address_space(3))) void*)(&As[p ^ 1][(i * NT + tid) * 8]),
            16, 0, 0);
    }

    // ---- MFMA cluster ks=0 ----
    {
      const int qa = ((kh ^ (fr & 7)) << 3);   // swizzled A chunk, ks=0
      bhalf8 a[4], b[4];
#pragma unroll
      for (int mi = 0; mi < 4; ++mi)
        a[mi] = *(const bhalf8*)(&Ac[(wm * 64 + mi * 16 + fr) * BK + qa]);
#pragma unroll
      for (int ni = 0; ni < 4; ++ni)
        b[ni] = *(const bhalf8*)(&Bc[(wn * 64 + ni * 16 + fr) * BST + kh * 8]);
      __builtin_amdgcn_s_setprio(1);
#pragma unroll
      for (int mi = 0; mi < 4; ++mi)
#pragma unroll
        for (int ni = 0; ni < 4; ++ni)
          acc[mi][ni] = __builtin_amdgcn_mfma_f32_16x16x32_bf16(a[mi], b[ni], acc[mi][ni], 0, 0, 0);
      __builtin_amdgcn_s_setprio(0);
    }

    // ---- dequant tile t+1 into Bs[p^1] (VALU overlaps MFMA pipes) ----
    if (more) {
      unsigned int qq[2] = { qv0, qv1 };
#pragma unroll
      for (int i = 0; i < 2; ++i) {
        const unsigned int q = qq[i];
        uint4 pk; unsigned int w[4];
#pragma unroll
        for (int j = 0; j < 4; ++j) {
          const float f0 = fmaf((float)((q >> (8 * j))     & 15u), sN, zN);
          const float f1 = fmaf((float)((q >> (8 * j + 4)) & 15u), sN, zN);
          w[j] = cvt_pk_bf16(f0, f1);
        }
        pk.x = w[0]; pk.y = w[1]; pk.z = w[2]; pk.w = w[3];
        *(uint4*)(&Bs[p ^ 1][bc * BST + (br + i * 4) * 8]) = pk;
      }
    }

    // ---- MFMA cluster ks=1 ----
    {
      const int qa = (((4 + kh) ^ (fr & 7)) << 3);   // swizzled A chunk, ks=1
      bhalf8 a[4], b[4];
#pragma unroll
      for (int mi = 0; mi < 4; ++mi)
        a[mi] = *(const bhalf8*)(&Ac[(wm * 64 + mi * 16 + fr) * BK + qa]);
#pragma unroll
      for (int ni = 0; ni < 4; ++ni)
        b[ni] = *(const bhalf8*)(&Bc[(wn * 64 + ni * 16 + fr) * BST + 32 + kh * 8]);
      __builtin_amdgcn_s_setprio(1);
#pragma unroll
      for (int mi = 0; mi < 4; ++mi)
#pragma unroll
        for (int ni = 0; ni < 4; ++ni)
          acc[mi][ni] = __builtin_amdgcn_mfma_f32_16x16x32_bf16(a[mi], b[ni], acc[mi][ni], 0, 0, 0);
      __builtin_amdgcn_s_setprio(0);
    }

    __syncthreads();   // drains DMA vmcnt + dequant lgkm; flips buffers
  }

  // ---- epilogue: +bias, store f32 (C/D: col=lane&15, row=kh*4+e) ----
#pragma unroll
  for (int ni = 0; ni < 4; ++ni) {
    const int col = n0 + wn * 64 + ni * 16 + fr;
    const float bsv = bias[col];
#pragma unroll
    for (int mi = 0; mi < 4; ++mi) {
      const int rowb = m0 + wm * 64 + mi * 16 + kh * 4;
#pragma unroll
      for (int e = 0; e < 4; ++e)
        out[(size_t)(rowb + e) * Ndim + col] = acc[mi][ni][e] + bsv;
    }
  }
}

// ---------------- fallback: round-4 fused kernel (validated, 950us) --------
__global__ __launch_bounds__(NT, 1)
void qgemm_fused(const float*         __restrict__ x,
                 const unsigned int*  __restrict__ qweight,
                 const unsigned int*  __restrict__ qzeros,
                 const float*         __restrict__ scales,
                 const float*         __restrict__ bias,
                 float*               __restrict__ out)
{
  __shared__ unsigned short As[BM * AST];
  __shared__ unsigned short Bs[BN * BST];

  const int tid  = threadIdx.x;
  const int lane = tid & 63;
  const int wid  = tid >> 6;
  const int wm   = wid >> 1;
  const int wn   = wid & 1;
  const int fr   = lane & 15;
  const int kh   = lane >> 4;

  const int nbn = Ndim / BN;
  const int nwg = (Mdim / BM) * nbn;
  const int bid = blockIdx.x;
  const int swz = (bid & 7) * (nwg >> 3) + (bid >> 3);
  const int m0  = (swz / nbn) * BM;
  const int n0  = (swz % nbn) * BN;

  const int ar = tid >> 3;
  const int ac = (tid & 7) * 8;
  const float* xbase = x + (size_t)(m0 + ar) * Kdim + ac;

  const int bc = tid & 127;
  const int br = tid >> 7;
  const int nn = n0 + bc;

  floatx4 acc[4][4] = {};

  for (int kt = 0; kt < Kdim / BK; ++kt) {
    const int k0 = kt * BK;
    __syncthreads();

    float4 av[4][2];
#pragma unroll
    for (int i = 0; i < 4; ++i) {
      const float* p = xbase + (size_t)i * 64 * Kdim + k0;
      av[i][0] = *(const float4*)(p);
      av[i][1] = *(const float4*)(p + 4);
    }

    const int g = k0 >> 7;
    const float        s  = scales[(size_t)g * Ndim + nn];
    const unsigned int qz = qzeros[(size_t)g * (Ndim / 8) + (nn >> 3)];
    const float        zc = -(float)((qz >> ((nn & 7) * 4)) & 15u) * s;
    unsigned int qv[2];
    qv[0] = qweight[(size_t)(k0 / 8 + br)     * Ndim + nn];
    qv[1] = qweight[(size_t)(k0 / 8 + br + 4) * Ndim + nn];

#pragma unroll
    for (int i = 0; i < 4; ++i) {
      uint4 pk;
      pk.x = cvt_pk_bf16(av[i][0].x, av[i][0].y);
      pk.y = cvt_pk_bf16(av[i][0].z, av[i][0].w);
      pk.z = cvt_pk_bf16(av[i][1].x, av[i][1].y);
      pk.w = cvt_pk_bf16(av[i][1].z, av[i][1].w);
      *(uint4*)(&As[(ar + i * 64) * AST + ac]) = pk;
    }

#pragma unroll
    for (int i = 0; i < 2; ++i) {
      const unsigned int q = qv[i];
      const int r = br + i * 4;
      uint4 pk;
      unsigned int w[4];
#pragma unroll
      for (int j = 0; j < 4; ++j) {
        const float f0 = fmaf((float)((q >> (8 * j))     & 15u), s, zc);
        const float f1 = fmaf((float)((q >> (8 * j + 4)) & 15u), s, zc);
        w[j] = cvt_pk_bf16(f0, f1);
      }
      pk.x = w[0]; pk.y = w[1]; pk.z = w[2]; pk.w = w[3];
      *(uint4*)(&Bs[bc * BST + r * 8]) = pk;
    }
    __syncthreads();

#pragma unroll
    for (int ks = 0; ks < BK / 32; ++ks) {
      bhalf8 a[4], b[4];
#pragma unroll
      for (int mi = 0; mi < 4; ++mi)
        a[mi] = *(const bhalf8*)(&As[(wm * 64 + mi * 16 + fr) * AST + ks * 32 + kh * 8]);
#pragma unroll
      for (int ni = 0; ni < 4; ++ni)
        b[ni] = *(const bhalf8*)(&Bs[(wn * 64 + ni * 16 + fr) * BST + ks * 32 + kh * 8]);
#pragma unroll
      for (int mi = 0; mi < 4; ++mi)
#pragma unroll
        for (int ni = 0; ni < 4; ++ni)
          acc[mi][ni] = __builtin_amdgcn_mfma_f32_16x16x32_bf16(a[mi], b[ni], acc[mi][ni], 0, 0, 0);
    }
  }

#pragma unroll
  for (int ni = 0; ni < 4; ++ni) {
    const int col = n0 + wn * 64 + ni * 16 + fr;
    const float bsv = bias[col];
#pragma unroll
    for (int mi = 0; mi < 4; ++mi) {
      const int rowb = m0 + wm * 64 + mi * 16 + kh * 4;
#pragma unroll
      for (int e = 0; e < 4; ++e)
        out[(size_t)(rowb + e) * Ndim + col] = acc[mi][ni][e] + bsv;
    }
  }
}

extern "C" void kernel_launch(void* const* d_in, const int* in_sizes, int n_in,
                              void* d_out, int out_size, void* d_ws, size_t ws_size,
                              hipStream_t stream) {
  const float*        x       = (const float*)d_in[0];
  const unsigned int* qweight = (const unsigned int*)d_in[1];
  const unsigned int* qzeros  = (const unsigned int*)d_in[2];
  const float*        scales  = (const float*)d_in[3];
  // d_in[4] = g_idx: arange(K)//128, recomputed in-kernel as k>>7
  const float*        bias    = (const float*)d_in[5];
  float*              outp    = (float*)d_out;

  const int nwg = (Mdim / BM) * (Ndim / BN);   // 2752

  if (ws_size >= XB_BYTES) {
    unsigned short* xb = (unsigned short*)d_ws;
    cvt_x_kernel<<<dim3(2048), dim3(256), 0, stream>>>(x, xb);
    qgemm_db<<<dim3(nwg), dim3(NT), 0, stream>>>(xb, qweight, qzeros, scales, bias, outp);
  } else {
    qgemm_fused<<<dim3(nwg), dim3(NT), 0, stream>>>(x, qweight, qzeros, scales, bias, outp);
  }
}